// Round 6
// baseline (772.404 us; speedup 1.0000x reference)
//
#include <hip/hip_runtime.h>

// PatternLearner on MI355X (gfx950). Inputs fp32, outputs fp32.
// d_out = [output0 (N*H) | output1=pattern (N*H)] fp32.
// Scratch-in-d_out: patb(bf16) bytes [0,12.58M), w1t..w2td bytes [12.58M,22.02M)
// — inside output0's byte range, overwritten only by the final exp0.
// R6: dist_topk v7 = v6 (reg top-16 + log-lb filter, 2-D grid for L2) +
// 2-phase stage-ahead double-buffer (stage K-step t+1 BEFORE computing t;
// barrier drain lands after ~350cyc of ds_read+MFMA cover). cand LDS aliases
// buf1 (chunk ends are always odd t -> buf1 is the just-consumed half), so
// LDS stays ~50.7KB -> 3 blocks/CU. gemm_bt keeps R3 stage-ahead.

#define N_TOK 8192
#define HDIM  768
#define H2DIM 1536
#define PMEM  8192
#define KTOP  16
#define DSPLIT 8
#define CHUNK_N 128
#define DCHUNKS (PMEM/DSPLIT/CHUNK_N)   // 8
#define BKD 64
#define KSTEPS (HDIM/BKD)               // 12

typedef __attribute__((ext_vector_type(8))) short bf16x8;   // 8 bf16 = 4 VGPRs
typedef __attribute__((ext_vector_type(4))) float f32x4;
typedef unsigned short u16;
typedef unsigned int   u32;

__device__ __forceinline__ float bf2f(u16 u){ return __uint_as_float(((u32)u)<<16); }
__device__ __forceinline__ u16 f2bf(float f){
  u32 x = __float_as_uint(f);
  return (u16)((x + 0x7FFFu + ((x>>16)&1u)) >> 16);   // RNE
}
__device__ __forceinline__ void lds_dma16(const void* g, void* l){
  __builtin_amdgcn_global_load_lds(
      (const __attribute__((address_space(1))) void*)g,
      (__attribute__((address_space(3))) void*)l, 16, 0, 0);
}

__device__ __forceinline__ float block_sum(float s){
  #pragma unroll
  for (int o=32;o;o>>=1) s += __shfl_xor(s,o);
  __shared__ float ps[4];
  int tid = threadIdx.x;
  if ((tid&63)==0) ps[tid>>6] = s;
  __syncthreads();
  return ps[0]+ps[1]+ps[2]+ps[3];
}

// ---- log0: v = atanh(nc)*x/nc. fp32 in, bf16 out ----
__global__ __launch_bounds__(256) void log0_rows(const float* __restrict__ in, u16* __restrict__ out){
  int r = blockIdx.x, tid = threadIdx.x;
  size_t ro = (size_t)r*HDIM;
  float v0=in[ro+tid], v1=in[ro+tid+256], v2=in[ro+tid+512];
  float s = block_sum(v0*v0+v1*v1+v2*v2);
  float n = sqrtf(s);
  float nc = fminf(fmaxf(n, 1e-5f), 1.0f-1e-5f);
  float sc = atanhf(nc)/nc;
  u16* orow = out + ro;
  orow[tid]=f2bf(v0*sc); orow[tid+256]=f2bf(v1*sc); orow[tid+512]=f2bf(v2*sc);
}

// ---- exp0: y = tanh(nm)*x/nm. bf16 in; fp32 out (+optional bf16 copy, a2/iva)
__global__ __launch_bounds__(256) void exp0_rows(const u16* __restrict__ in, float* __restrict__ outf,
                                                 u16* outb, float* a2p, float* ivp){
  int r = blockIdx.x, tid = threadIdx.x;
  const u16* row = in + (size_t)r*HDIM;
  float v0=bf2f(row[tid]), v1=bf2f(row[tid+256]), v2=bf2f(row[tid+512]);
  float s = block_sum(v0*v0+v1*v1+v2*v2);
  float n = sqrtf(s);
  float nm = fmaxf(n, 1e-5f);
  float sc = tanhf(nm)/nm;
  size_t ro = (size_t)r*HDIM;
  outf[ro+tid]=v0*sc; outf[ro+tid+256]=v1*sc; outf[ro+tid+512]=v2*sc;
  if (outb != nullptr){
    outb[ro+tid]=f2bf(v0*sc); outb[ro+tid+256]=f2bf(v1*sc); outb[ro+tid+512]=f2bf(v2*sc);
  }
  if (a2p != nullptr && tid==0){
    float a2 = fminf(sc*sc*s, 1.0f-1e-5f);
    a2p[r] = a2; ivp[r] = 1.0f/(1.0f-a2);
  }
}

// ---- memory prep: memb(bf16), pmeta = {b2, 1/(1-b2), sigmoid(imp), 0} ----
__global__ __launch_bounds__(256) void prep_mem(const float* __restrict__ mem, const float* __restrict__ imp,
                                                u16* __restrict__ memb, float4* __restrict__ pmeta){
  int p = blockIdx.x, tid = threadIdx.x;
  size_t ro = (size_t)p*HDIM;
  float v0=mem[ro+tid], v1=mem[ro+tid+256], v2=mem[ro+tid+512];
  memb[ro+tid]=f2bf(v0); memb[ro+tid+256]=f2bf(v1); memb[ro+tid+512]=f2bf(v2);
  float s = block_sum(v0*v0+v1*v1+v2*v2);
  if (tid==0){
    float b2 = fminf(s, 1.0f-1e-5f);
    float4 m; m.x=b2; m.y=1.0f/(1.0f-b2); m.z=1.0f/(1.0f+__expf(-imp[p])); m.w=0.f;
    pmeta[p]=m;
  }
}

// ---- LayerNorm + exact gelu over rows of 1536; in-place safe ----
__global__ __launch_bounds__(256) void ln_gelu(const u16* __restrict__ in, const float* __restrict__ g,
                                               const float* __restrict__ be, u16* __restrict__ out){
  int r = blockIdx.x, tid = threadIdx.x;
  const u16* row = in + (size_t)r*H2DIM;
  float h[6]; float s=0.f, s2=0.f;
  #pragma unroll
  for (int j=0;j<6;j++){ float v=bf2f(row[tid+256*j]); h[j]=v; s+=v; s2+=v*v; }
  #pragma unroll
  for (int o=32;o;o>>=1){ s += __shfl_xor(s,o); s2 += __shfl_xor(s2,o); }
  __shared__ float ps[4], ps2[4];
  if ((tid&63)==0){ ps[tid>>6]=s; ps2[tid>>6]=s2; }
  __syncthreads();
  s = ps[0]+ps[1]+ps[2]+ps[3]; s2 = ps2[0]+ps2[1]+ps2[2]+ps2[3];
  float mu  = s*(1.0f/H2DIM);
  float var = fmaxf(s2*(1.0f/H2DIM) - mu*mu, 0.0f);
  float rstd = rsqrtf(var + 1e-5f);
  u16* orow = out + (size_t)r*H2DIM;
  #pragma unroll
  for (int j=0;j<6;j++){
    int c = tid+256*j;
    float y = (h[j]-mu)*rstd*g[c] + be[c];
    float ge = 0.5f*y*(1.0f + erff(y*0.70710678118654752f));
    orow[c] = f2bf(ge);
  }
}

// ---- GEMM: C[M,N] = A[M,K]*BT[N,K]^T + bias; bf16 in/out, fp32 acc/bias ----
// m97 structure + stage-ahead double-buffer (R3; kept — non-dist time 374->340us).
__global__ __launch_bounds__(256,2) void gemm_bt(
    const u16* __restrict__ A, const u16* __restrict__ B,
    const float* __restrict__ bias, u16* __restrict__ C,
    int M, int Nn, int Kk)
{
  __shared__ u16 As[2][128*64];   // 2 x 16 KB
  __shared__ u16 Bs[2][128*64];   // 2 x 16 KB
  const int tid = threadIdx.x;
  const int m0 = blockIdx.y*128, n0 = blockIdx.x*128;
  const int wave = tid>>6, lane = tid&63;
  const int wm = (wave>>1)*64, wn = (wave&1)*64;
  const int col = lane&15, quad = lane>>4;
  const int nst = Kk>>6;

  int sr[4], sk[4];
  #pragma unroll
  for (int j=0;j<4;j++){
    int c = j*256 + wave*64 + lane;
    int r = c>>3, kc = c&7;
    sr[j] = r; sk[j] = (kc ^ (r&7))*8;
  }

  #pragma unroll
  for (int j=0;j<4;j++){
    lds_dma16(A + (size_t)(m0+sr[j])*Kk + sk[j], &As[0][(j*256 + wave*64)*8]);
    lds_dma16(B + (size_t)(n0+sr[j])*Kk + sk[j], &Bs[0][(j*256 + wave*64)*8]);
  }
  __syncthreads();

  f32x4 acc[4][4] = {};
  for (int t=0; t<nst; t++){
    if (t+1 < nst){
      const int k0n = (t+1)<<6;
      const int bn = (t+1)&1;
      #pragma unroll
      for (int j=0;j<4;j++){
        lds_dma16(A + (size_t)(m0+sr[j])*Kk + k0n + sk[j], &As[bn][(j*256 + wave*64)*8]);
        lds_dma16(B + (size_t)(n0+sr[j])*Kk + k0n + sk[j], &Bs[bn][(j*256 + wave*64)*8]);
      }
    }
    const u16* Ac = &As[t&1][0];
    const u16* Bc = &Bs[t&1][0];
    #pragma unroll
    for (int kk=0;kk<2;kk++){
      const int kq = kk*4 + quad;
      bf16x8 af[4], bfr[4];
      #pragma unroll
      for (int i=0;i<4;i++){
        int ar = wm + i*16 + col;
        af[i]  = *(const bf16x8*)&Ac[ar*64 + ((kq ^ (ar&7))*8)];
      }
      #pragma unroll
      for (int j=0;j<4;j++){
        int br = wn + j*16 + col;
        bfr[j] = *(const bf16x8*)&Bc[br*64 + ((kq ^ (br&7))*8)];
      }
      #pragma unroll
      for (int i=0;i<4;i++)
        #pragma unroll
        for (int j=0;j<4;j++)
          acc[i][j] = __builtin_amdgcn_mfma_f32_16x16x32_bf16(af[i], bfr[j], acc[i][j], 0,0,0);
    }
    __syncthreads();
  }
  #pragma unroll
  for (int j=0;j<4;j++){
    int cc = n0 + wn + j*16 + col;
    float bv = bias[cc];
    #pragma unroll
    for (int i=0;i<4;i++){
      int rbase = m0 + wm + i*16 + quad*4;
      #pragma unroll
      for (int rr=0;rr<4;rr++)
        C[(size_t)(rbase+rr)*Nn + cc] = f2bf(acc[i][j][rr] + bv);
    }
  }
}

// ---- transpose fp32 -> bf16 ----
__global__ __launch_bounds__(256) void transpose_f2b(const float* __restrict__ in, u16* __restrict__ out,
                                                     int R, int Ccols){
  __shared__ float tile[32][33];
  int tx = threadIdx.x & 31, ty = threadIdx.x >> 5;
  int c0 = blockIdx.x*32, r0 = blockIdx.y*32;
  #pragma unroll
  for (int i=0;i<32;i+=8) tile[ty+i][tx] = in[(size_t)(r0+ty+i)*Ccols + c0+tx];
  __syncthreads();
  #pragma unroll
  for (int i=0;i<32;i+=8) out[(size_t)(c0+ty+i)*R + r0+tx] = f2bf(tile[tx][ty+i]);
}

// ---- dist_topk v7: v6 + 2-phase stage-ahead dbuf, cand aliases buf1 ----
// grid (N_TOK/64, DSPLIT) — consecutive bids share slice -> L2-friendly.
// Flat K-step loop t=0..95 (8 chunks x 12 steps): stage(t+1 -> buf[(t+1)&1])
// BEFORE mfma(buf[t&1]); single __syncthreads per step (drain covered by
// ds_read+MFMA). Chunk ends at odd t (ks=11 -> t=12c+11), so buf1 is always
// the just-consumed half at selection -> cand[4][64][17] aliases buf1.
// LDS: 48KB bufs + masks/a2s ≈ 50.7KB -> 3 blocks/CU.
// packed key = (dist_f32_bits & ~0x1FFF) | pattern_idx.
__global__ __launch_bounds__(256,3) void dist_topk(
    const u16* __restrict__ patb, const u16* __restrict__ memb,
    const float* __restrict__ a2f, const float* __restrict__ iva,
    const float4* __restrict__ pmeta, u32* __restrict__ plist)
{
  __shared__ char usm[49152];        // [A0 8K][B0 16K][A1 8K][B1 16K]
  typedef u32 cand_t[64][17];
  cand_t* cand = (cand_t*)(usm + 24576);   // aliases buf1 (A1+B1), 17.4KB
  __shared__ u32 masks[4][64];
  __shared__ float a2s[4][16], iv2[4][16];
  const int tid = threadIdx.x;
  const int wave = tid>>6, lane = tid&63;
  const int col = lane&15, quad = lane>>4;
  const int t0 = blockIdx.x*64;
  const int s  = blockIdx.y;
  const int pb0 = s*(PMEM/DSPLIT);
  if (lane<16){
    a2s[wave][lane] = a2f[t0 + wave*16 + lane];
    iv2[wave][lane] = 2.0f*iva[t0 + wave*16 + lane];
  }
  u32 lst[16];
  #pragma unroll
  for (int j=0;j<16;j++) lst[j] = 0xFFFFFFFFu;
  __syncthreads();
  float a2r[4], ivr[4];
  #pragma unroll
  for (int rr=0;rr<4;rr++){ a2r[rr]=a2s[wave][quad*4+rr]; ivr[rr]=iv2[wave][quad*4+rr]; }

  // per-lane staging coords (A: 2 chunks, B: 4 chunks of 256 16B-lanes)
  int arr[2], ask[2], brr[4], bsk[4];
  #pragma unroll
  for (int j=0;j<2;j++){
    int c = j*256 + wave*64 + lane;
    int r = c>>3, kc = c&7;
    arr[j] = r; ask[j] = (kc ^ (r&7))*8;
  }
  #pragma unroll
  for (int j=0;j<4;j++){
    int c = j*256 + wave*64 + lane;
    int r = c>>3, kc = c&7;
    brr[j] = r; bsk[j] = (kc ^ (r&7))*8;
  }

  // prologue: stage (nc=0, ks=0) into buf0
  {
    u16* Ad = (u16*)usm;
    u16* Bd = (u16*)(usm + 8192);
    #pragma unroll
    for (int j=0;j<2;j++)
      lds_dma16(patb + (size_t)(t0+arr[j])*HDIM + ask[j], Ad + (j*256 + wave*64)*8);
    #pragma unroll
    for (int j=0;j<4;j++)
      lds_dma16(memb + (size_t)(pb0+brr[j])*HDIM + bsk[j], Bd + (j*256 + wave*64)*8);
  }
  __syncthreads();

  f32x4 acc[8];
  int ks = 0, pbase = pb0;
  for (int t=0; t<DCHUNKS*KSTEPS; t++){
    int ksn = ks+1, pbn = pbase;
    if (ksn==KSTEPS){ ksn = 0; pbn += CHUNK_N; }
    if (t+1 < DCHUNKS*KSTEPS){
      const int k0n = ksn*BKD;
      const int pn = (t+1)&1;
      u16* Ad = (u16*)(usm + pn*24576);
      u16* Bd = (u16*)(usm + 8192 + pn*24576);
      #pragma unroll
      for (int j=0;j<2;j++)
        lds_dma16(patb + (size_t)(t0+arr[j])*HDIM + k0n + ask[j], Ad + (j*256 + wave*64)*8);
      #pragma unroll
      for (int j=0;j<4;j++)
        lds_dma16(memb + (size_t)(pbn+brr[j])*HDIM + k0n + bsk[j], Bd + (j*256 + wave*64)*8);
    }
    if (ks==0){
      #pragma unroll
      for (int j=0;j<8;j++) acc[j] = (f32x4){0.f,0.f,0.f,0.f};
    }
    // MFMA: 16 tokens x 128 patterns per wave, K=64, from buf t&1
    {
      const int pc = t&1;
      const u16* Ac = (const u16*)(usm + pc*24576);
      const u16* Bc = (const u16*)(usm + 8192 + pc*24576);
      #pragma unroll
      for (int kk=0;kk<2;kk++){
        const int kq = kk*4 + quad;
        const int ar = wave*16 + col;
        bf16x8 a = *(const bf16x8*)&Ac[ar*64 + ((kq ^ (ar&7))*8)];
        #pragma unroll
        for (int j=0;j<8;j++){
          const int br = j*16 + col;
          bf16x8 b = *(const bf16x8*)&Bc[br*64 + ((kq ^ (br&7))*8)];
          acc[j] = __builtin_amdgcn_mfma_f32_16x16x32_bf16(a, b, acc[j], 0,0,0);
        }
      }
    }
    __syncthreads();   // drains prefetch (after ds_read+MFMA cover) + orders buffers

    if (ks == KSTEPS-1){
      // selection: two passes of 64 patterns (j<4, j>=4).
      // cand aliases buf1 = just-consumed half (t odd here); no DMA outstanding.
      #pragma unroll
      for (int p=0;p<2;p++){
        u32 thrU[4];
        #pragma unroll
        for (int rr=0;rr<4;rr++) thrU[rr] = (u32)__shfl((int)lst[15], quad*4+rr);
        u32 mask = 0;
        #pragma unroll
        for (int j4=0;j4<4;j4++){
          const int j = p*4 + j4;
          const int pglob = pbase + j*16 + col;
          float4 mt = pmeta[pglob];
          #pragma unroll
          for (int rr=0;rr<4;rr++){
            float num = fmaxf(a2r[rr] + mt.x - 2.0f*acc[j][rr], 0.0f);
            float arg = fmaf(num, ivr[rr]*mt.y, 1.0f);
            arg = fmaxf(arg, 1.0000001f);
            // lower bound: acosh(arg) >= log(arg) -> safe reject
            float lb = __logf(arg) * mt.z;
            u32 lbT = __float_as_uint(lb) & 0xFFFFE000u;
            if (lbT < thrU[rr]){
              float d = __logf(arg + sqrtf((arg-1.0f)*(arg+1.0f))) * mt.z;  // acosh*sig
              u32 key = (__float_as_uint(d) & 0xFFFFE000u) | (u32)pglob;
              if (key < thrU[rr]){
                cand[wave][j4*16+col][quad*4+rr] = key;
                mask |= 1u << (j4*4 + rr);
              }
            }
          }
        }
        masks[wave][lane] = mask;
        __syncthreads();
        if (lane < 16){                       // lane = token tt within wave
          const int g = lane>>2, rr = lane&3;
          u32 worst = lst[15];
          #pragma unroll 4
          for (int q=0;q<16;q++){
            u32 m = (masks[wave][g*16+q] >> rr) & 0x1111u;
            while (m){
              int b2 = __ffs(m)-1; m &= m-1;
              u32 v = cand[wave][(b2>>2)*16+q][lane];
              if (v < worst){
                u32 tv = v;
                #pragma unroll
                for (int jj=0;jj<16;jj++){
                  u32 a = lst[jj];
                  u32 mn = tv < a ? tv : a;
                  u32 mx = tv < a ? a : tv;
                  lst[jj] = mn; tv = mx;
                }
                worst = lst[15];
              }
            }
          }
        }
        __syncthreads();
      }
    }
    ks = ksn; pbase = pbn;
  }
  if (lane < 16){
    u32* dst = plist + ((size_t)(t0 + wave*16 + lane)*DSPLIT + s)*16;
    #pragma unroll
    for (int j=0;j<16;j++) dst[j] = lst[j];
  }
}

// ---- fused: merge DSPLIT lists/token, gather, log0 ----
__global__ __launch_bounds__(256) void gather_log0(
    const u32* __restrict__ plist, const u16* __restrict__ memb, u16* __restrict__ out)
{
  __shared__ u32 keysh[DSPLIT*16];           // 128 keys
  __shared__ float wsh[KTOP]; __shared__ int ish[KTOP];
  int n = blockIdx.x, tid = threadIdx.x;
  if (tid < DSPLIT*16) keysh[tid] = plist[(size_t)n*DSPLIT*16 + tid];
  __syncthreads();
  if (tid == 0){
    int ptr[DSPLIT];
    #pragma unroll
    for (int i=0;i<DSPLIT;i++) ptr[i]=0;
    #pragma unroll
    for (int j=0;j<KTOP;j++){
      u32 best = 0xFFFFFFFFu; int bw = 0;
      #pragma unroll
      for (int i=0;i<DSPLIT;i++){
        u32 v = (ptr[i]<16) ? keysh[i*16+ptr[i]] : 0xFFFFFFFFu;
        if (v < best){ best = v; bw = i; }
      }
      ptr[bw]++;
      wsh[j] = __expf(-__uint_as_float(best & 0xFFFFE000u));
      ish[j] = (int)(best & 0x1FFFu);
    }
  }
  __syncthreads();
  float v[3];
  #pragma unroll
  for (int j=0;j<3;j++){
    int cdx = tid + 256*j;
    float sv = 0.f;
    #pragma unroll
    for (int k=0;k<KTOP;k++) sv += wsh[k]*bf2f(memb[(size_t)ish[k]*HDIM + cdx]);
    v[j] = sv;
  }
  float ss = block_sum(v[0]*v[0]+v[1]*v[1]+v[2]*v[2]);
  float nn = sqrtf(ss);
  float nc = fminf(fmaxf(nn, 1e-5f), 1.0f-1e-5f);
  float sc = atanhf(nc)/nc;
  #pragma unroll
  for (int j=0;j<3;j++) out[(size_t)n*HDIM + tid + 256*j] = f2bf(v[j]*sc);
}

extern "C" void kernel_launch(void* const* d_in, const int* in_sizes, int n_in,
                              void* d_out, int out_size, void* d_ws, size_t ws_size,
                              hipStream_t stream)
{
  const float* x    = (const float*)d_in[0];
  const float* ew1  = (const float*)d_in[1];
  const float* eb1  = (const float*)d_in[2];
  const float* eg   = (const float*)d_in[3];
  const float* ebe  = (const float*)d_in[4];
  const float* ew2  = (const float*)d_in[5];
  const float* eb2  = (const float*)d_in[6];
  const float* dw1  = (const float*)d_in[7];
  const float* db1  = (const float*)d_in[8];
  const float* dg   = (const float*)d_in[9];
  const float* dbe  = (const float*)d_in[10];
  const float* dw2  = (const float*)d_in[11];
  const float* db2  = (const float*)d_in[12];
  const float* mem  = (const float*)d_in[13];
  const float* imp  = (const float*)d_in[14];

  const size_t NE = (size_t)N_TOK*HDIM;       // 6,291,456
  float* out0 = (float*)d_out;                // fp32 output 0
  float* out1 = out0 + NE;                    // fp32 output 1 (pattern)
  u16* patb = (u16*)d_out;                    // bf16 pattern, inside output0 range
  const size_t SWE = (size_t)HDIM*H2DIM;
  u16* w1t  = (u16*)d_out + NE;
  u16* w2t  = w1t + SWE;
  u16* w1td = w1t + 2*SWE;
  u16* w2td = w1t + 3*SWE;                    // ends < output0 end

  char* w = (char*)d_ws;
  size_t off = 0;
  u16* vbuf = (u16*)(w+off); off += NE*2;                    // bf16; also h2 alias
  u16* h1b  = (u16*)(w+off); off += (size_t)N_TOK*H2DIM*2;   // bf16; ln_gelu in-place
  u16* memb = h1b;                                            // alias: live enc-end..gather
  float* a2f = (float*)(w+off); off += (size_t)N_TOK*4;
  float* iva = (float*)(w+off); off += (size_t)N_TOK*4;
  off = (off+15)&~(size_t)15;
  float4* pmeta = (float4*)(w+off); off += (size_t)PMEM*16;
  u32* plist = (u32*)(w+off); off += (size_t)N_TOK*DSPLIT*16*4;  // 4 MB
  (void)in_sizes; (void)n_in; (void)out_size; (void)ws_size;

  dim3 blk(256);
  transpose_f2b<<<dim3(H2DIM/32, HDIM/32), blk, 0, stream>>>(ew1, w1t,  HDIM,  H2DIM);
  transpose_f2b<<<dim3(HDIM/32, H2DIM/32), blk, 0, stream>>>(ew2, w2t,  H2DIM, HDIM);
  transpose_f2b<<<dim3(H2DIM/32, HDIM/32), blk, 0, stream>>>(dw1, w1td, HDIM,  H2DIM);
  transpose_f2b<<<dim3(HDIM/32, H2DIM/32), blk, 0, stream>>>(dw2, w2td, H2DIM, HDIM);
  // encoder
  log0_rows<<<N_TOK, blk, 0, stream>>>(x, vbuf);
  gemm_bt<<<dim3(H2DIM/128, N_TOK/128), blk, 0, stream>>>(vbuf, w1t, eb1, h1b, N_TOK, H2DIM, HDIM);
  ln_gelu<<<N_TOK, blk, 0, stream>>>(h1b, eg, ebe, h1b);
  gemm_bt<<<dim3(HDIM/128, N_TOK/128), blk, 0, stream>>>(h1b, w2t, eb2, vbuf, N_TOK, HDIM, H2DIM);
  exp0_rows<<<N_TOK, blk, 0, stream>>>(vbuf, out1, patb, a2f, iva);
  // retrieval (memb aliases h1b — dead between encoder and decoder)
  prep_mem<<<PMEM, blk, 0, stream>>>(mem, imp, memb, pmeta);
  dist_topk<<<dim3(N_TOK/64, DSPLIT), blk, 0, stream>>>(patb, memb, a2f, iva, pmeta, plist);
  gather_log0<<<N_TOK, blk, 0, stream>>>(plist, memb, vbuf);
  // decoder
  gemm_bt<<<dim3(H2DIM/128, N_TOK/128), blk, 0, stream>>>(vbuf, w1td, db1, h1b, N_TOK, H2DIM, HDIM);
  ln_gelu<<<N_TOK, blk, 0, stream>>>(h1b, dg, dbe, h1b);
  gemm_bt<<<dim3(HDIM/128, N_TOK/128), blk, 0, stream>>>(h1b, w2td, db2, vbuf, N_TOK, HDIM, H2DIM);
  exp0_rows<<<N_TOK, blk, 0, stream>>>(vbuf, out0, nullptr, nullptr, nullptr);
}

// Round 7
// 720.057 us; speedup vs baseline: 1.0727x; 1.0727x over previous
//
#include <hip/hip_runtime.h>

// PatternLearner on MI355X (gfx950). Inputs fp32, outputs fp32.
// d_out = [output0 (N*H) | output1=pattern (N*H)] fp32.
// Scratch-in-d_out: patb(bf16) bytes [0,12.58M), w1t..w2td bytes [12.58M,22.02M)
// — inside output0's byte range, overwritten only by the final exp0.
// R7: dist_topk v8 = v6 (R5, single-buffer staging — R6 dbuf reverted) with:
//  (a) wave retile 16x128 -> 32x64 (2x2 wave grid): LDS reads/step 18->12,
//      per-wave top-16 covers a pattern-half -> NLIST=16 merge in gather (R2-proven),
//  (b) log2-space keys (key = log2(w)*sig, monotone; gather uses exp2f -> same weights),
//  (c) cand LDS aliases the dead A/B tiles during selection -> LDS 26.1KB,
//      residency VGPR-limited ~5 blocks/CU (was LDS-limited at 3),
//  (d) merge phase on 32 lanes (was 16).

#define N_TOK 8192
#define HDIM  768
#define H2DIM 1536
#define PMEM  8192
#define KTOP  16
#define DSPLIT 8
#define CHUNK_N 128
#define DCHUNKS (PMEM/DSPLIT/CHUNK_N)   // 8
#define BKD 64
#define KSTEPS (HDIM/BKD)               // 12
#define NLIST (DSPLIT*2)                // 16 sorted lists per token

typedef __attribute__((ext_vector_type(8))) short bf16x8;   // 8 bf16 = 4 VGPRs
typedef __attribute__((ext_vector_type(4))) float f32x4;
typedef unsigned short u16;
typedef unsigned int   u32;

__device__ __forceinline__ float bf2f(u16 u){ return __uint_as_float(((u32)u)<<16); }
__device__ __forceinline__ u16 f2bf(float f){
  u32 x = __float_as_uint(f);
  return (u16)((x + 0x7FFFu + ((x>>16)&1u)) >> 16);   // RNE
}
__device__ __forceinline__ void lds_dma16(const void* g, void* l){
  __builtin_amdgcn_global_load_lds(
      (const __attribute__((address_space(1))) void*)g,
      (__attribute__((address_space(3))) void*)l, 16, 0, 0);
}

__device__ __forceinline__ float block_sum(float s){
  #pragma unroll
  for (int o=32;o;o>>=1) s += __shfl_xor(s,o);
  __shared__ float ps[4];
  int tid = threadIdx.x;
  if ((tid&63)==0) ps[tid>>6] = s;
  __syncthreads();
  return ps[0]+ps[1]+ps[2]+ps[3];
}

// ---- log0: v = atanh(nc)*x/nc. fp32 in, bf16 out ----
__global__ __launch_bounds__(256) void log0_rows(const float* __restrict__ in, u16* __restrict__ out){
  int r = blockIdx.x, tid = threadIdx.x;
  size_t ro = (size_t)r*HDIM;
  float v0=in[ro+tid], v1=in[ro+tid+256], v2=in[ro+tid+512];
  float s = block_sum(v0*v0+v1*v1+v2*v2);
  float n = sqrtf(s);
  float nc = fminf(fmaxf(n, 1e-5f), 1.0f-1e-5f);
  float sc = atanhf(nc)/nc;
  u16* orow = out + ro;
  orow[tid]=f2bf(v0*sc); orow[tid+256]=f2bf(v1*sc); orow[tid+512]=f2bf(v2*sc);
}

// ---- exp0: y = tanh(nm)*x/nm. bf16 in; fp32 out (+optional bf16 copy, a2/iva)
__global__ __launch_bounds__(256) void exp0_rows(const u16* __restrict__ in, float* __restrict__ outf,
                                                 u16* outb, float* a2p, float* ivp){
  int r = blockIdx.x, tid = threadIdx.x;
  const u16* row = in + (size_t)r*HDIM;
  float v0=bf2f(row[tid]), v1=bf2f(row[tid+256]), v2=bf2f(row[tid+512]);
  float s = block_sum(v0*v0+v1*v1+v2*v2);
  float n = sqrtf(s);
  float nm = fmaxf(n, 1e-5f);
  float sc = tanhf(nm)/nm;
  size_t ro = (size_t)r*HDIM;
  outf[ro+tid]=v0*sc; outf[ro+tid+256]=v1*sc; outf[ro+tid+512]=v2*sc;
  if (outb != nullptr){
    outb[ro+tid]=f2bf(v0*sc); outb[ro+tid+256]=f2bf(v1*sc); outb[ro+tid+512]=f2bf(v2*sc);
  }
  if (a2p != nullptr && tid==0){
    float a2 = fminf(sc*sc*s, 1.0f-1e-5f);
    a2p[r] = a2; ivp[r] = 1.0f/(1.0f-a2);
  }
}

// ---- memory prep: memb(bf16), pmeta = {b2, 1/(1-b2), sigmoid(imp), 0} ----
__global__ __launch_bounds__(256) void prep_mem(const float* __restrict__ mem, const float* __restrict__ imp,
                                                u16* __restrict__ memb, float4* __restrict__ pmeta){
  int p = blockIdx.x, tid = threadIdx.x;
  size_t ro = (size_t)p*HDIM;
  float v0=mem[ro+tid], v1=mem[ro+tid+256], v2=mem[ro+tid+512];
  memb[ro+tid]=f2bf(v0); memb[ro+tid+256]=f2bf(v1); memb[ro+tid+512]=f2bf(v2);
  float s = block_sum(v0*v0+v1*v1+v2*v2);
  if (tid==0){
    float b2 = fminf(s, 1.0f-1e-5f);
    float4 m; m.x=b2; m.y=1.0f/(1.0f-b2); m.z=1.0f/(1.0f+__expf(-imp[p])); m.w=0.f;
    pmeta[p]=m;
  }
}

// ---- LayerNorm + exact gelu over rows of 1536; in-place safe ----
__global__ __launch_bounds__(256) void ln_gelu(const u16* __restrict__ in, const float* __restrict__ g,
                                               const float* __restrict__ be, u16* __restrict__ out){
  int r = blockIdx.x, tid = threadIdx.x;
  const u16* row = in + (size_t)r*H2DIM;
  float h[6]; float s=0.f, s2=0.f;
  #pragma unroll
  for (int j=0;j<6;j++){ float v=bf2f(row[tid+256*j]); h[j]=v; s+=v; s2+=v*v; }
  #pragma unroll
  for (int o=32;o;o>>=1){ s += __shfl_xor(s,o); s2 += __shfl_xor(s2,o); }
  __shared__ float ps[4], ps2[4];
  if ((tid&63)==0){ ps[tid>>6]=s; ps2[tid>>6]=s2; }
  __syncthreads();
  s = ps[0]+ps[1]+ps[2]+ps[3]; s2 = ps2[0]+ps2[1]+ps2[2]+ps2[3];
  float mu  = s*(1.0f/H2DIM);
  float var = fmaxf(s2*(1.0f/H2DIM) - mu*mu, 0.0f);
  float rstd = rsqrtf(var + 1e-5f);
  u16* orow = out + (size_t)r*H2DIM;
  #pragma unroll
  for (int j=0;j<6;j++){
    int c = tid+256*j;
    float y = (h[j]-mu)*rstd*g[c] + be[c];
    float ge = 0.5f*y*(1.0f + erff(y*0.70710678118654752f));
    orow[c] = f2bf(ge);
  }
}

// ---- GEMM: C[M,N] = A[M,K]*BT[N,K]^T + bias; bf16 in/out, fp32 acc/bias ----
// m97 structure + stage-ahead double-buffer (R3; kept — non-dist time 374->340us).
__global__ __launch_bounds__(256,2) void gemm_bt(
    const u16* __restrict__ A, const u16* __restrict__ B,
    const float* __restrict__ bias, u16* __restrict__ C,
    int M, int Nn, int Kk)
{
  __shared__ u16 As[2][128*64];   // 2 x 16 KB
  __shared__ u16 Bs[2][128*64];   // 2 x 16 KB
  const int tid = threadIdx.x;
  const int m0 = blockIdx.y*128, n0 = blockIdx.x*128;
  const int wave = tid>>6, lane = tid&63;
  const int wm = (wave>>1)*64, wn = (wave&1)*64;
  const int col = lane&15, quad = lane>>4;
  const int nst = Kk>>6;

  int sr[4], sk[4];
  #pragma unroll
  for (int j=0;j<4;j++){
    int c = j*256 + wave*64 + lane;
    int r = c>>3, kc = c&7;
    sr[j] = r; sk[j] = (kc ^ (r&7))*8;
  }

  #pragma unroll
  for (int j=0;j<4;j++){
    lds_dma16(A + (size_t)(m0+sr[j])*Kk + sk[j], &As[0][(j*256 + wave*64)*8]);
    lds_dma16(B + (size_t)(n0+sr[j])*Kk + sk[j], &Bs[0][(j*256 + wave*64)*8]);
  }
  __syncthreads();

  f32x4 acc[4][4] = {};
  for (int t=0; t<nst; t++){
    if (t+1 < nst){
      const int k0n = (t+1)<<6;
      const int bn = (t+1)&1;
      #pragma unroll
      for (int j=0;j<4;j++){
        lds_dma16(A + (size_t)(m0+sr[j])*Kk + k0n + sk[j], &As[bn][(j*256 + wave*64)*8]);
        lds_dma16(B + (size_t)(n0+sr[j])*Kk + k0n + sk[j], &Bs[bn][(j*256 + wave*64)*8]);
      }
    }
    const u16* Ac = &As[t&1][0];
    const u16* Bc = &Bs[t&1][0];
    #pragma unroll
    for (int kk=0;kk<2;kk++){
      const int kq = kk*4 + quad;
      bf16x8 af[4], bfr[4];
      #pragma unroll
      for (int i=0;i<4;i++){
        int ar = wm + i*16 + col;
        af[i]  = *(const bf16x8*)&Ac[ar*64 + ((kq ^ (ar&7))*8)];
      }
      #pragma unroll
      for (int j=0;j<4;j++){
        int br = wn + j*16 + col;
        bfr[j] = *(const bf16x8*)&Bc[br*64 + ((kq ^ (br&7))*8)];
      }
      #pragma unroll
      for (int i=0;i<4;i++)
        #pragma unroll
        for (int j=0;j<4;j++)
          acc[i][j] = __builtin_amdgcn_mfma_f32_16x16x32_bf16(af[i], bfr[j], acc[i][j], 0,0,0);
    }
    __syncthreads();
  }
  #pragma unroll
  for (int j=0;j<4;j++){
    int cc = n0 + wn + j*16 + col;
    float bv = bias[cc];
    #pragma unroll
    for (int i=0;i<4;i++){
      int rbase = m0 + wm + i*16 + quad*4;
      #pragma unroll
      for (int rr=0;rr<4;rr++)
        C[(size_t)(rbase+rr)*Nn + cc] = f2bf(acc[i][j][rr] + bv);
    }
  }
}

// ---- transpose fp32 -> bf16 ----
__global__ __launch_bounds__(256) void transpose_f2b(const float* __restrict__ in, u16* __restrict__ out,
                                                     int R, int Ccols){
  __shared__ float tile[32][33];
  int tx = threadIdx.x & 31, ty = threadIdx.x >> 5;
  int c0 = blockIdx.x*32, r0 = blockIdx.y*32;
  #pragma unroll
  for (int i=0;i<32;i+=8) tile[ty+i][tx] = in[(size_t)(r0+ty+i)*Ccols + c0+tx];
  __syncthreads();
  #pragma unroll
  for (int i=0;i<32;i+=8) out[(size_t)(c0+ty+i)*R + r0+tx] = f2bf(tile[tx][ty+i]);
}

// ---- dist_topk v8: 32x64 wave tile, log2 keys, tile/cand LDS union ----
// grid (N_TOK/64, DSPLIT). Block: 64 tokens x 128-pattern chunks; wave w =
// (wr=w>>1 token-half, wc=w&1 pattern-half) owns 32 tokens x 64 patterns.
// K staged in steps of 64 via global_load_lds with XOR chunk swizzle (as R5).
// Per step per wave: 4 A-reads + 8 B-reads (vs 18 at 16x128). Lane t<32 keeps
// its token's top-16 of this wave's pattern-half in registers; gather merges
// NLIST=16 lists. Keys in log2-space: key=(bits(log2(w)*sig)&~0x1FFF)|idx —
// monotone in d; gather weight = exp2f(-keyval) == exp(-d) exactly.
// Filter: log2(arg) <= log2(w) (acosh lower bound) -> safe reject.
__global__ __launch_bounds__(256,3) void dist_topk(
    const u16* __restrict__ patb, const u16* __restrict__ memb,
    const float* __restrict__ a2f, const float* __restrict__ iva,
    const float4* __restrict__ pmeta, u32* __restrict__ plist)
{
  __shared__ char usm[24576];            // [Atile 8K][Btile 16K] / cand union
  u16* Atile = (u16*)usm;                // 64 x 64, swizzled
  u16* Btile = (u16*)(usm + 8192);       // 128 x 64, swizzled
  typedef u32 cand_t[32][33];
  cand_t* cand = (cand_t*)usm;           // [wave][pcol 0..31][token 0..31], 16.9KB
  __shared__ u32 masks[4][64];
  __shared__ float a2s[64], iv2[64];
  const int tid = threadIdx.x;
  const int wave = tid>>6, lane = tid&63;
  const int col = lane&15, quad = lane>>4;
  const int wr = wave>>1, wc = wave&1;   // token-half, pattern-half
  const int t0 = blockIdx.x*64;
  const int s  = blockIdx.y;
  const int pb0 = s*(PMEM/DSPLIT);
  if (tid < 64){ a2s[tid] = a2f[t0+tid]; iv2[tid] = 2.0f*iva[t0+tid]; }
  u32 lst[16];
  #pragma unroll
  for (int j=0;j<16;j++) lst[j] = 0xFFFFFFFFu;
  __syncthreads();
  // per-lane invariants for the 8 tokens this lane scores (t = wr*32+i*16+quad*4+rr)
  float a2r[2][4], ivr[2][4];
  #pragma unroll
  for (int i=0;i<2;i++)
    #pragma unroll
    for (int rr=0;rr<4;rr++){
      int t = wr*32 + i*16 + quad*4 + rr;
      a2r[i][rr] = a2s[t]; ivr[i][rr] = iv2[t];
    }

  for (int nc=0; nc<DCHUNKS; nc++){
    const int pbase = pb0 + nc*CHUNK_N;
    f32x4 acc[2][4] = {};
    for (int ks=0; ks<KSTEPS; ks++){
      const int k0 = ks*BKD;
      __syncthreads();                      // tiles free (prev MFMA / selection done)
      #pragma unroll
      for (int j=0;j<2;j++){
        int c = j*256 + wave*64 + lane;
        int r = c>>3, kc = c&7;
        const u16* src = patb + (size_t)(t0+r)*HDIM + k0 + ((kc ^ (r&7))*8);
        lds_dma16(src, Atile + (size_t)(j*256 + wave*64)*8);
      }
      #pragma unroll
      for (int j=0;j<4;j++){
        int c = j*256 + wave*64 + lane;
        int r = c>>3, kc = c&7;
        const u16* src = memb + (size_t)(pbase+r)*HDIM + k0 + ((kc ^ (r&7))*8);
        lds_dma16(src, Btile + (size_t)(j*256 + wave*64)*8);
      }
      __syncthreads();                      // vmcnt(0) drained before barrier
      #pragma unroll
      for (int kk=0;kk<2;kk++){
        const int kq = kk*4 + quad;
        bf16x8 af[2], bfr[4];
        #pragma unroll
        for (int i=0;i<2;i++){
          int ar = wr*32 + i*16 + col;
          af[i] = *(const bf16x8*)&Atile[ar*64 + ((kq ^ (ar&7))*8)];
        }
        #pragma unroll
        for (int j=0;j<4;j++){
          int br = wc*64 + j*16 + col;
          bfr[j] = *(const bf16x8*)&Btile[br*64 + ((kq ^ (br&7))*8)];
        }
        #pragma unroll
        for (int i=0;i<2;i++)
          #pragma unroll
          for (int j=0;j<4;j++)
            acc[i][j] = __builtin_amdgcn_mfma_f32_16x16x32_bf16(af[i], bfr[j], acc[i][j], 0,0,0);
      }
    }
    __syncthreads();   // all tile reads done before cand (union) is written
    // selection: two passes of 32 patterns (j = p*2 + j4)
    #pragma unroll
    for (int p=0;p<2;p++){
      u32 thrU[2][4];
      #pragma unroll
      for (int i=0;i<2;i++)
        #pragma unroll
        for (int rr=0;rr<4;rr++)
          thrU[i][rr] = (u32)__shfl((int)lst[15], i*16 + quad*4 + rr);
      u32 mask = 0;
      #pragma unroll
      for (int j4=0;j4<2;j4++){
        const int j = p*2 + j4;
        const int pglob = pbase + wc*64 + j*16 + col;
        float4 mt = pmeta[pglob];
        #pragma unroll
        for (int i=0;i<2;i++){
          #pragma unroll
          for (int rr=0;rr<4;rr++){
            float num = fmaxf(a2r[i][rr] + mt.x - 2.0f*acc[i][j][rr], 0.0f);
            float arg = fmaf(num, ivr[i][rr]*mt.y, 1.0f);
            arg = fmaxf(arg, 1.0000001f);
            // lower bound: log2(w) >= log2(arg) -> safe reject
            float lb = __log2f(arg) * mt.z;
            u32 lbT = __float_as_uint(lb) & 0xFFFFE000u;
            if (lbT < thrU[i][rr]){
              float d = __log2f(arg + sqrtf((arg-1.0f)*(arg+1.0f))) * mt.z;  // acosh/ln2*sig
              u32 key = (__float_as_uint(d) & 0xFFFFE000u) | (u32)pglob;
              if (key < thrU[i][rr]){
                cand[wave][j4*16+col][i*16 + quad*4 + rr] = key;
                mask |= 1u << (j4*8 + i*4 + rr);
              }
            }
          }
        }
      }
      masks[wave][lane] = mask;
      __syncthreads();
      if (lane < 32){                       // lane = token t within wave
        const int i = lane>>4, q = (lane>>2)&3, rr = lane&3;
        const int sh = i*4 + rr;
        u32 worst = lst[15];
        #pragma unroll 4
        for (int c=0;c<16;c++){
          u32 m = (masks[wave][q*16+c] >> sh) & 0x101u;
          while (m){
            int b = __ffs(m)-1; m &= m-1;
            u32 v = cand[wave][(b>>3)*16+c][lane];
            if (v < worst){
              u32 tv = v;
              #pragma unroll
              for (int jj=0;jj<16;jj++){
                u32 a = lst[jj];
                u32 mn = tv < a ? tv : a;
                u32 mx = tv < a ? a : tv;
                lst[jj] = mn; tv = mx;
              }
              worst = lst[15];
            }
          }
        }
      }
      __syncthreads();
    }
  }
  if (lane < 32){
    u32* dst = plist + ((size_t)(t0 + wr*32 + lane)*NLIST + s*2 + wc)*16;
    #pragma unroll
    for (int j=0;j<16;j++) dst[j] = lst[j];
  }
}

// ---- fused: merge NLIST lists/token, gather, log0 ----
__global__ __launch_bounds__(256) void gather_log0(
    const u32* __restrict__ plist, const u16* __restrict__ memb, u16* __restrict__ out)
{
  __shared__ u32 keysh[NLIST*16];            // 256 keys
  __shared__ float wsh[KTOP]; __shared__ int ish[KTOP];
  int n = blockIdx.x, tid = threadIdx.x;
  keysh[tid] = plist[(size_t)n*NLIST*16 + tid];
  __syncthreads();
  if (tid == 0){
    int ptr[NLIST];
    #pragma unroll
    for (int i=0;i<NLIST;i++) ptr[i]=0;
    #pragma unroll
    for (int j=0;j<KTOP;j++){
      u32 best = 0xFFFFFFFFu; int bw = 0;
      #pragma unroll
      for (int i=0;i<NLIST;i++){
        u32 v = (ptr[i]<16) ? keysh[i*16+ptr[i]] : 0xFFFFFFFFu;
        if (v < best){ best = v; bw = i; }
      }
      ptr[bw]++;
      wsh[j] = exp2f(-__uint_as_float(best & 0xFFFFE000u));   // exp(-d), log2 key
      ish[j] = (int)(best & 0x1FFFu);
    }
  }
  __syncthreads();
  float v[3];
  #pragma unroll
  for (int j=0;j<3;j++){
    int cdx = tid + 256*j;
    float sv = 0.f;
    #pragma unroll
    for (int k=0;k<KTOP;k++) sv += wsh[k]*bf2f(memb[(size_t)ish[k]*HDIM + cdx]);
    v[j] = sv;
  }
  float ss = block_sum(v[0]*v[0]+v[1]*v[1]+v[2]*v[2]);
  float nn = sqrtf(ss);
  float nc = fminf(fmaxf(nn, 1e-5f), 1.0f-1e-5f);
  float sc = atanhf(nc)/nc;
  #pragma unroll
  for (int j=0;j<3;j++) out[(size_t)n*HDIM + tid + 256*j] = f2bf(v[j]*sc);
}

extern "C" void kernel_launch(void* const* d_in, const int* in_sizes, int n_in,
                              void* d_out, int out_size, void* d_ws, size_t ws_size,
                              hipStream_t stream)
{
  const float* x    = (const float*)d_in[0];
  const float* ew1  = (const float*)d_in[1];
  const float* eb1  = (const float*)d_in[2];
  const float* eg   = (const float*)d_in[3];
  const float* ebe  = (const float*)d_in[4];
  const float* ew2  = (const float*)d_in[5];
  const float* eb2  = (const float*)d_in[6];
  const float* dw1  = (const float*)d_in[7];
  const float* db1  = (const float*)d_in[8];
  const float* dg   = (const float*)d_in[9];
  const float* dbe  = (const float*)d_in[10];
  const float* dw2  = (const float*)d_in[11];
  const float* db2  = (const float*)d_in[12];
  const float* mem  = (const float*)d_in[13];
  const float* imp  = (const float*)d_in[14];

  const size_t NE = (size_t)N_TOK*HDIM;       // 6,291,456
  float* out0 = (float*)d_out;                // fp32 output 0
  float* out1 = out0 + NE;                    // fp32 output 1 (pattern)
  u16* patb = (u16*)d_out;                    // bf16 pattern, inside output0 range
  const size_t SWE = (size_t)HDIM*H2DIM;
  u16* w1t  = (u16*)d_out + NE;
  u16* w2t  = w1t + SWE;
  u16* w1td = w1t + 2*SWE;
  u16* w2td = w1t + 3*SWE;                    // ends < output0 end

  char* w = (char*)d_ws;
  size_t off = 0;
  u16* vbuf = (u16*)(w+off); off += NE*2;                    // bf16; also h2 alias
  u16* h1b  = (u16*)(w+off); off += (size_t)N_TOK*H2DIM*2;   // bf16; ln_gelu in-place
  u16* memb = h1b;                                            // alias: live enc-end..gather
  float* a2f = (float*)(w+off); off += (size_t)N_TOK*4;
  float* iva = (float*)(w+off); off += (size_t)N_TOK*4;
  off = (off+15)&~(size_t)15;
  float4* pmeta = (float4*)(w+off); off += (size_t)PMEM*16;
  u32* plist = (u32*)(w+off); off += (size_t)N_TOK*NLIST*16*4;  // 8 MB
  (void)in_sizes; (void)n_in; (void)out_size; (void)ws_size;

  dim3 blk(256);
  transpose_f2b<<<dim3(H2DIM/32, HDIM/32), blk, 0, stream>>>(ew1, w1t,  HDIM,  H2DIM);
  transpose_f2b<<<dim3(HDIM/32, H2DIM/32), blk, 0, stream>>>(ew2, w2t,  H2DIM, HDIM);
  transpose_f2b<<<dim3(H2DIM/32, HDIM/32), blk, 0, stream>>>(dw1, w1td, HDIM,  H2DIM);
  transpose_f2b<<<dim3(HDIM/32, H2DIM/32), blk, 0, stream>>>(dw2, w2td, H2DIM, HDIM);
  // encoder
  log0_rows<<<N_TOK, blk, 0, stream>>>(x, vbuf);
  gemm_bt<<<dim3(H2DIM/128, N_TOK/128), blk, 0, stream>>>(vbuf, w1t, eb1, h1b, N_TOK, H2DIM, HDIM);
  ln_gelu<<<N_TOK, blk, 0, stream>>>(h1b, eg, ebe, h1b);
  gemm_bt<<<dim3(HDIM/128, N_TOK/128), blk, 0, stream>>>(h1b, w2t, eb2, vbuf, N_TOK, HDIM, H2DIM);
  exp0_rows<<<N_TOK, blk, 0, stream>>>(vbuf, out1, patb, a2f, iva);
  // retrieval (memb aliases h1b — dead between encoder and decoder)
  prep_mem<<<PMEM, blk, 0, stream>>>(mem, imp, memb, pmeta);
  dist_topk<<<dim3(N_TOK/64, DSPLIT), blk, 0, stream>>>(patb, memb, a2f, iva, pmeta, plist);
  gather_log0<<<N_TOK, blk, 0, stream>>>(plist, memb, vbuf);
  // decoder
  gemm_bt<<<dim3(H2DIM/128, N_TOK/128), blk, 0, stream>>>(vbuf, w1td, db1, h1b, N_TOK, H2DIM, HDIM);
  ln_gelu<<<N_TOK, blk, 0, stream>>>(h1b, dg, dbe, h1b);
  gemm_bt<<<dim3(HDIM/128, N_TOK/128), blk, 0, stream>>>(h1b, w2td, db2, vbuf, N_TOK, HDIM, H2DIM);
  exp0_rows<<<N_TOK, blk, 0, stream>>>(vbuf, out0, nullptr, nullptr, nullptr);
}